// Round 2
// baseline (75.709 us; speedup 1.0000x reference)
//
#include <hip/hip_runtime.h>

// SU2 attention, MI355X.
// Math: logits.real = dot4(normed_i, normed_j); x in [-0.7071, 0.7071] so
// softmax needs NO max-subtraction -> partial (l, acc) combine by plain sum.
// Round 2: output written PLANAR — d_out = [all 32768 reals (b,i,h,d order),
// then all 32768 imags] — matching np.stack([out.real, out.imag]) layout.

#define S 2048
#define H 8
#define QR 8   // queries per wave (register-tiled)

__device__ inline float fast_exp2(float x) {
#if __has_builtin(__builtin_amdgcn_exp2f)
    return __builtin_amdgcn_exp2f(x);
#else
    return exp2f(x);
#endif
}

// Repack inputs: kv[h*2048+j] = normalized 4-vector, vv[...] = raw 4-vector.
__global__ __launch_bounds__(256) void su2_prep(const float* __restrict__ re,
                                                const float* __restrict__ im,
                                                float4* __restrict__ kv,
                                                float4* __restrict__ vv) {
    int t = blockIdx.x * 256 + threadIdx.x;   // t = h*2048 + j, t in [0,16384)
    int h = t >> 11;
    int j = t & 2047;
    int src = (j * H + h) * 2;                // input layout (j, h, d)
    float r0 = re[src], r1 = re[src + 1];
    float i0 = im[src], i1 = im[src + 1];
    float ss = r0 * r0 + i0 * i0 + r1 * r1 + i1 * i1;
    float inv = rsqrtf(ss);
    kv[t] = make_float4(r0 * inv, i0 * inv, r1 * inv, i1 * inv);
    vv[t] = make_float4(r0, i0, r1, i1);
}

// One wave per 8 queries; j-dimension split over 64 lanes (32 iters).
// grid = (64, 8): x = query group (4 waves x 8 q = 32 q/block), y = head.
__global__ __launch_bounds__(256) void su2_attn(const float4* __restrict__ kv,
                                                const float4* __restrict__ vv,
                                                float2* __restrict__ outr,
                                                float2* __restrict__ outi) {
    const int h    = blockIdx.y;
    const int lane = threadIdx.x & 63;
    const int wave = threadIdx.x >> 6;
    const int i_base = (blockIdx.x * 4 + wave) * QR;

    const float4* __restrict__ kvh = kv + (h << 11);
    const float4* __restrict__ vvh = vv + (h << 11);

    // 8 normalized query vectors — wave-uniform loads
    float4 q[QR];
#pragma unroll
    for (int r = 0; r < QR; ++r) q[r] = kvh[i_base + r];

    float  l[QR];
    float4 acc[QR];
#pragma unroll
    for (int r = 0; r < QR; ++r) {
        l[r] = 0.f;
        acc[r] = make_float4(0.f, 0.f, 0.f, 0.f);
    }

    // c = SCALE * log2(e) so exp(x*SCALE) = exp2(x*c)
    const float c = 0.70710678118654752440f * 1.44269504088896340736f;

#pragma unroll 4
    for (int jj = 0; jj < S / 64; ++jj) {
        int j = jj * 64 + lane;
        float4 k = kvh[j];
        float4 v = vvh[j];
#pragma unroll
        for (int r = 0; r < QR; ++r) {
            float d = q[r].x * k.x + q[r].y * k.y + q[r].z * k.z + q[r].w * k.w;
            float p = fast_exp2(d * c);
            l[r] += p;
            acc[r].x += p * v.x;
            acc[r].y += p * v.y;
            acc[r].z += p * v.z;
            acc[r].w += p * v.w;
        }
    }

    // Butterfly sum all-reduce across the 64 lanes (plain sums — no max state)
#pragma unroll
    for (int r = 0; r < QR; ++r) {
#pragma unroll
        for (int m = 32; m >= 1; m >>= 1) {
            l[r]     += __shfl_xor(l[r], m, 64);
            acc[r].x += __shfl_xor(acc[r].x, m, 64);
            acc[r].y += __shfl_xor(acc[r].y, m, 64);
            acc[r].z += __shfl_xor(acc[r].z, m, 64);
            acc[r].w += __shfl_xor(acc[r].w, m, 64);
        }
    }

    if (lane == 0) {
#pragma unroll
        for (int r = 0; r < QR; ++r) {
            float inv = 1.0f / l[r];
            int i = i_base + r;
            // planar: real plane then imag plane, each (i, h, d) -> float2
            outr[i * H + h] = make_float2(acc[r].x * inv, acc[r].z * inv);
            outi[i * H + h] = make_float2(acc[r].y * inv, acc[r].w * inv);
        }
    }
}

extern "C" void kernel_launch(void* const* d_in, const int* in_sizes, int n_in,
                              void* d_out, int out_size, void* d_ws, size_t ws_size,
                              hipStream_t stream) {
    const float* re = (const float*)d_in[0];
    const float* im = (const float*)d_in[1];
    float4* kv = (float4*)d_ws;          // 16384 float4 = 256 KB
    float4* vv = kv + S * H;             // +256 KB (ws needs 512 KB total)
    float2* outr = (float2*)d_out;       // reals: 32768 floats = 16384 float2
    float2* outi = outr + S * H;         // imags: next 32768 floats

    su2_prep<<<dim3(64), dim3(256), 0, stream>>>(re, im, kv, vv);
    su2_attn<<<dim3(S / 32, H), dim3(256), 0, stream>>>(kv, vv, outr, outi);
}